// Round 11
// baseline (468.036 us; speedup 1.0000x reference)
//
#include <hip/hip_runtime.h>
#include <math.h>

typedef unsigned short ushort_t;

// Problem constants (fixed shapes from setup_inputs)
constexpr int B_  = 2;
constexpr int L_  = 512;    // txt tokens
constexpr int N_  = 2048;   // img tokens (H=64, W=32)
constexpr int T_  = 2560;   // L_+N_
constexpr int D_  = 512;
constexpr int NH_ = 4;
constexpr int HD_ = 128;
constexpr int FF_ = 2048;
constexpr int SIXD = 3072;
constexpr int MROWS = B_ * T_;   // 5120
#define SCALE_ 0.08838834764831843f

// Workspace layout (floats). Activations stored as separate bf16 hi/lo planes.
constexpr size_t QSZ    = (size_t)B_ * NH_ * T_ * HD_;      // 2,621,440 (== B*T*D)
constexpr size_t O_ETXT = 0;
constexpr size_t O_EIMG = O_ETXT + (size_t)B_ * SIXD;       // 6144
constexpr size_t O_MOD  = O_EIMG + (size_t)B_ * SIXD;       // 12288
constexpr size_t O_EFF  = O_MOD + (size_t)B_ * NH_ * N_;    // 28672
constexpr size_t O_XN   = O_EFF + 16;                        // xn planes (hi|lo) -> later Wmlp planes
constexpr size_t O_Q    = O_XN + QSZ;                        // Q bf16 hi/lo planes (pre-scaled, roped); AT planes after comb
constexpr size_t O_K    = O_Q + QSZ;                         // attn partial O (ks=0)
constexpr size_t O_V    = O_K + QSZ;                         // f32 V; attn partial O (ks=1) during attn
constexpr size_t O_ATTN = O_V + QSZ;                         // Wqkv planes; attn partial O (ks=2)
constexpr size_t O_X2   = O_ATTN + QSZ;                      // f32 X2 (after proj); Vt bf16 during attn
constexpr size_t O_XIN2 = O_X2 + QSZ;                        // Kh/Kl planes (from QKV epi); xin2 planes later
constexpr size_t O_H    = O_Q;   // H planes (hi|lo, 4*QSZ ushorts each) over Q..ATTN span
constexpr size_t O_ML   = O_X2 + QSZ / 2;                    // (m,l) per [ks][bh][row], after Vt

// Weight plane geometry (ushort offsets)
constexpr size_t WQ_STREAM = (size_t)SIXD / 2 * D_;          // 1536*512 = 786432
constexpr size_t WQ_TOTAL  = 2 * WQ_STREAM;                  // 1,572,864 (hi plane size)
constexpr size_t WM_PROJ   = 0;                              // proj: 2 x 512*512
constexpr size_t WM_PROJ_S = (size_t)D_ * D_;                // 262144
constexpr size_t WM_FC1    = WM_PROJ + 2 * WM_PROJ_S;        // 524288
constexpr size_t WM_FC1_S  = (size_t)FF_ * D_;               // 1048576
constexpr size_t WM_FC2    = WM_FC1 + 2 * WM_FC1_S;          // 2621440
constexpr size_t WM_FC2_S  = (size_t)D_ * FF_;               // 1048576

typedef short bf16x8 __attribute__((ext_vector_type(8)));
typedef float f32x4 __attribute__((ext_vector_type(4)));

__device__ __forceinline__ ushort_t f2bf_rne(float x) {
  unsigned u = __float_as_uint(x);
  u += 0x7fff + ((u >> 16) & 1);
  return (ushort_t)(u >> 16);
}

// async global->LDS, 16B per lane; LDS dest = wave-uniform base + lane*16 (HW rule)
__device__ __forceinline__ void gload_lds16(const ushort_t* g, ushort_t* l) {
  __builtin_amdgcn_global_load_lds(
      (const __attribute__((address_space(1))) void*)g,
      (__attribute__((address_space(3))) void*)l, 16, 0, 0);
}

// ---------------- stage0: adaln + mod/eff + Wqkv hi/lo split (all input-only deps) ----------------
__global__ __launch_bounds__(256) void k_stage0(
    const float* __restrict__ vec,
    const float* __restrict__ wt, const float* __restrict__ bt,
    const float* __restrict__ wi, const float* __restrict__ bi,
    const float* __restrict__ sspat, const float* __restrict__ mw,
    const float* __restrict__ mb, const float* __restrict__ stemp,
    const float* __restrict__ qkvwt, const float* __restrict__ qkvwi,
    float* __restrict__ ws) {
  int blk = blockIdx.x;
  if (blk < 48) {
    // ---- adaLN: e = silu(vec) @ W.T + b ----
    int s = blk / 24;
    int rem = blk % 24;
    int b = rem / 12;
    int o = (rem % 12) * 256 + threadIdx.x;
    __shared__ float sv[D_];
    for (int i = threadIdx.x; i < D_; i += 256) {
      float x = vec[b * D_ + i];
      sv[i] = x / (1.0f + __expf(-x));
    }
    __syncthreads();
    const float* w = (s == 0) ? wt : wi;
    const float* bb = (s == 0) ? bt : bi;
    const float4* wrow = (const float4*)(w + (size_t)o * D_);
    float acc = 0.f;
    for (int d4 = 0; d4 < D_ / 4; ++d4) {
      float4 wv = wrow[d4];
      int d = d4 * 4;
      acc += wv.x * sv[d] + wv.y * sv[d + 1] + wv.z * sv[d + 2] + wv.w * sv[d + 3];
    }
    acc += bb[o];
    float* e = ws + ((s == 0) ? O_ETXT : O_EIMG);
    e[b * SIXD + o] = acc;
  } else if (blk < 112) {
    // ---- mod (bilinear upsample + affine + clip + exp) and eff ----
    int idx = (blk - 48) * 256 + threadIdx.x;  // B*NH*N = 16384
    if (idx < B_) {
      float s = 0.f;
      for (int h = 0; h < NH_; ++h) s += stemp[idx * NH_ + h];
      float t = fmaxf(s * 0.25f, 0.1f);
      ws[O_EFF + idx] = SCALE_ / t;
    }
    int b = idx / (NH_ * N_);
    int h = (idx / N_) % NH_;
    int n = idx % N_;
    int y = n >> 5;      // W=32
    int x = n & 31;
    float fy = (y + 0.5f) * 0.125f - 0.5f;
    float fx = (x + 0.5f) * 0.25f  - 0.5f;
    float y0f = floorf(fy), x0f = floorf(fx);
    float wy = fy - y0f, wx = fx - x0f;
    int y0 = (int)y0f, x0 = (int)x0f;
    int iy0 = y0 < 0 ? 0 : y0, iy1 = (y0 + 1) > 7 ? 7 : (y0 + 1);
    int ix0 = x0 < 0 ? 0 : x0, ix1 = (x0 + 1) > 7 ? 7 : (x0 + 1);
    const float* S = sspat + b * 64;
    float v00 = S[iy0*8+ix0], v01 = S[iy0*8+ix1];
    float v10 = S[iy1*8+ix0], v11 = S[iy1*8+ix1];
    float up = (1.f-wy)*((1.f-wx)*v00 + wx*v01) + wy*((1.f-wx)*v10 + wx*v11);
    float m = up * mw[h] + mb[h];
    m = fminf(fmaxf(m, -2.f), 2.f);
    ws[O_MOD + idx] = __expf(m);
  } else {
    // ---- Wqkv f32 -> bf16 hi/lo planes (into O_ATTN region, dead until attn) ----
    int g = (blk - 112) * 256 + threadIdx.x;   // 0 .. 393215 float4-groups
    int s = g >= (int)(WQ_STREAM / 4);
    const float4* src = (const float4*)(s ? qkvwi : qkvwt);
    float4 v = src[g - s * (int)(WQ_STREAM / 4)];
    ushort4 hh, ll;
    hh.x = f2bf_rne(v.x); hh.y = f2bf_rne(v.y); hh.z = f2bf_rne(v.z); hh.w = f2bf_rne(v.w);
    ll.x = f2bf_rne(v.x - __uint_as_float((unsigned)hh.x << 16));
    ll.y = f2bf_rne(v.y - __uint_as_float((unsigned)hh.y << 16));
    ll.z = f2bf_rne(v.z - __uint_as_float((unsigned)hh.z << 16));
    ll.w = f2bf_rne(v.w - __uint_as_float((unsigned)hh.w << 16));
    ushort_t* Wqh = (ushort_t*)(ws + O_ATTN);
    ushort_t* Wql = Wqh + WQ_TOTAL;
    *(ushort4*)&Wqh[(size_t)g * 4] = hh;
    *(ushort4*)&Wql[(size_t)g * 4] = ll;
  }
}

// ---------------- rms + adaLN modulate -> bf16 hi/lo planes ----------------
template<bool FROM_INPUT>
__global__ __launch_bounds__(256) void k_rmsmod(const float* __restrict__ txt, const float* __restrict__ img,
                                                const float* __restrict__ src_ws,
                                                const float* __restrict__ nw_txt, const float* __restrict__ nw_img,
                                                int sh_off, int sc_off,
                                                const float* __restrict__ e_ws,
                                                ushort_t* __restrict__ oh, ushort_t* __restrict__ ol) {
  int row = blockIdx.x;         // B*T rows
  int b = row / T_;
  int t = row % T_;
  bool is_txt = t < L_;
  int i0 = threadIdx.x * 2;
  float x0, x1;
  if (FROM_INPUT) {
    const float* src = is_txt ? (txt + ((size_t)b * L_ + t) * D_)
                              : (img + ((size_t)b * N_ + (t - L_)) * D_);
    x0 = src[i0]; x1 = src[i0 + 1];
  } else {
    const float* src = src_ws + (size_t)row * D_;
    x0 = src[i0]; x1 = src[i0 + 1];
  }
  float ss = x0 * x0 + x1 * x1;
  for (int off = 32; off; off >>= 1) ss += __shfl_down(ss, off, 64);
  __shared__ float red[4];
  if ((threadIdx.x & 63) == 0) red[threadIdx.x >> 6] = ss;
  __syncthreads();
  float tot = red[0] + red[1] + red[2] + red[3];
  float r = rsqrtf(tot * (1.0f / D_) + 1e-6f);
  const float* e = e_ws + (is_txt ? O_ETXT : O_EIMG) + (size_t)b * SIXD;
  const float* nw = is_txt ? nw_txt : nw_img;
  float y0 = x0 * r * nw[i0]     * (1.f + e[sc_off + i0])     + e[sh_off + i0];
  float y1 = x1 * r * nw[i0 + 1] * (1.f + e[sc_off + i0 + 1]) + e[sh_off + i0 + 1];
  ushort_t h0 = f2bf_rne(y0), h1 = f2bf_rne(y1);
  ushort_t l0 = f2bf_rne(y0 - __uint_as_float((unsigned)h0 << 16));
  ushort_t l1 = f2bf_rne(y1 - __uint_as_float((unsigned)h1 << 16));
  *(unsigned*)&oh[(size_t)row * D_ + i0] = (unsigned)h0 | ((unsigned)h1 << 16);
  *(unsigned*)&ol[(size_t)row * D_ + i0] = (unsigned)l0 | ((unsigned)l1 << 16);
}

// ---------------- templated MFMA GEMM: single-buffered gl_lds staging, MTILE param ----------------
// EPI: 0 = QKV fused epilogue: rope+mod via __shfl_xor(1); Q pre-SCALED bf16 hi/lo planes ->
//          O_Q (scale = SCALE_ or eff[b], applied in f32 before split => bit-identical to the
//          old attn-side conversion), K bf16 hi/lo planes -> O_XIN2, V f32. biast = rope table.
//      1 = proj gate+residual->X2,  2 = fc1 bias+gelu->H planes,  3 = fc2 bias+gate+residual->out
template<int MTILE, int NTILE, int NTERMS, int KDIM, int NPR, int EPI>
__global__ __launch_bounds__(256) void k_gemm(
    const ushort_t* __restrict__ Aph, const ushort_t* __restrict__ Apl,
    const ushort_t* __restrict__ Wth, const ushort_t* __restrict__ Wtl,
    const ushort_t* __restrict__ Wih, const ushort_t* __restrict__ Wil,
    const float* __restrict__ biast, const float* __restrict__ biasi,
    const float* __restrict__ ws_ro, float* __restrict__ wsw,
    const float* __restrict__ txt, const float* __restrict__ img,
    ushort_t* __restrict__ Hph, ushort_t* __restrict__ Hpl, float* __restrict__ outf) {
  int mt = blockIdx.x / NPR, nt = blockIdx.x % NPR;
  int row0 = mt * MTILE;
  int col0 = nt * NTILE;
  int b = row0 / T_;
  int t0 = row0 % T_;
  bool is_txt = t0 < L_;   // L_=512 divisible by MTILE -> tiles never straddle
  const ushort_t* Wh = is_txt ? Wth : Wih;
  const ushort_t* Wl = (NTERMS == 3) ? (is_txt ? Wtl : Wil) : nullptr;

  __shared__ __align__(16) ushort_t ash[MTILE * 32];
  __shared__ __align__(16) ushort_t asl[MTILE * 32];
  __shared__ __align__(16) ushort_t bsh[NTILE * 32];
  __shared__ __align__(16) ushort_t bsl[(NTERMS == 3) ? NTILE * 32 : 8];

  int tid = threadIdx.x;
  int w = tid >> 6, lane = tid & 63, quad = lane >> 4, lc = lane & 15;
  int rh = w >> 1, ch = w & 1;
  constexpr int NFR = NTILE / 32;
  constexpr int MR  = MTILE / 32;

  // staging lane geometry: lane l lands at LDS row chunk*16+(l>>2), stored slot l&3;
  // its global source is the LOGICAL slot (l&3)^((l>>3)&3)  [(row>>1)&3 with chunk*16≡0]
  int Rloc  = lane >> 2;
  int lslot = (lane & 3) ^ ((lane >> 3) & 3);
  // ds_read: want logical slot=quad at row ar (ar≡lc mod 16, base mult of 16)
  int ssw = (quad ^ ((lc >> 1) & 3)) * 8;

  f32x4 acc[MR][NFR];
  #pragma unroll
  for (int m = 0; m < MR; ++m)
    #pragma unroll
    for (int n = 0; n < NFR; ++n) acc[m][n] = f32x4{0.f, 0.f, 0.f, 0.f};

  for (int kt = 0; kt < KDIM / 32; ++kt) {
    int scol = kt * 32 + lslot * 8;
    // ---- stage A hi/lo: MTILE/16 chunks of 16 rows, distributed across 4 waves ----
    #pragma unroll
    for (int cc = 0; cc < MTILE / 64; ++cc) {
      int c = w * (MTILE / 64) + cc;
      size_t goff = (size_t)(row0 + c * 16 + Rloc) * KDIM + scol;
      gload_lds16(Aph + goff, &ash[c * 512]);
      gload_lds16(Apl + goff, &asl[c * 512]);
    }
    // ---- stage W: NTILE/16 chunks distributed across 4 waves ----
    #pragma unroll
    for (int cc = 0; cc < NTILE / 64; ++cc) {
      int c = w + cc * 4;
      size_t goff = (size_t)(col0 + c * 16 + Rloc) * KDIM + scol;
      gload_lds16(Wh + goff, &bsh[c * 512]);
      if (NTERMS == 3) gload_lds16(Wl + goff, &bsl[c * 512]);
    }
    __syncthreads();

    bf16x8 afh[MR], afl[MR];
    #pragma unroll
    for (int m = 0; m < MR; ++m) {
      int ar = rh * (MTILE / 2) + m * 16 + lc;
      afh[m] = *(const bf16x8*)&ash[ar * 32 + ssw];
      afl[m] = *(const bf16x8*)&asl[ar * 32 + ssw];
    }
    #pragma unroll
    for (int n = 0; n < NFR; ++n) {
      int br = ch * (NTILE / 2) + n * 16 + lc;
      bf16x8 bh = *(const bf16x8*)&bsh[br * 32 + ssw];
      if (NTERMS == 3) {
        bf16x8 bl = *(const bf16x8*)&bsl[br * 32 + ssw];
        #pragma unroll
        for (int m = 0; m < MR; ++m) {
          acc[m][n] = __builtin_amdgcn_mfma_f32_16x16x32_bf16(afl[m], bh, acc[m][n], 0, 0, 0);
          acc[m][n] = __builtin_amdgcn_mfma_f32_16x16x32_bf16(afh[m], bl, acc[m][n], 0, 0, 0);
          acc[m][n] = __builtin_amdgcn_mfma_f32_16x16x32_bf16(afh[m], bh, acc[m][n], 0, 0, 0);
        }
      } else {
        #pragma unroll
        for (int m = 0; m < MR; ++m) {
          acc[m][n] = __builtin_amdgcn_mfma_f32_16x16x32_bf16(afl[m], bh, acc[m][n], 0, 0, 0);
          acc[m][n] = __builtin_amdgcn_mfma_f32_16x16x32_bf16(afh[m], bh, acc[m][n], 0, 0, 0);
        }
      }
    }
    __syncthreads();
  }

  const float* e = ws_ro + (is_txt ? O_ETXT : O_EIMG) + (size_t)b * SIXD;
  const float* bias = is_txt ? biast : biasi;
  #pragma unroll
  for (int m = 0; m < MR; ++m) {
    #pragma unroll
    for (int n = 0; n < NFR; ++n) {
      #pragma unroll
      for (int r = 0; r < 4; ++r) {
        int rg = row0 + rh * (MTILE / 2) + m * 16 + quad * 4 + r;
        int cg = col0 + ch * (NTILE / 2) + n * 16 + lc;
        float val = acc[m][n][r];
        int tt = rg % T_;
        if (EPI == 0) {
          // fused rope+mod + Q/K/V scatter. which/h block-uniform (128-aligned col tile).
          int which = cg >> 9, h = (cg >> 7) & 3, dd = cg & 127;
          float partner = __shfl_xor(val, 1, 64);   // value at dd^1 (lane^1)
          size_t pidx = (((size_t)b * NH_ + h) * T_ + tt) * HD_ + dd;
          if (which == 2) {
            wsw[O_V + pidx] = val;
          } else {
            if (tt >= L_) {
              int nn = tt - L_;
              float c = biast[(size_t)nn * HD_ + (dd & ~1)];      // rope table via biast
              float s = biast[(size_t)nn * HD_ + (dd & ~1) + 1];
              float mm = ws_ro[O_MOD + ((size_t)b * NH_ + h) * N_ + nn];
              val = ((dd & 1) ? (val * c + partner * s)
                              : (val * c - partner * s)) * mm;
            }
            if (which == 0) {
              // pre-scaled Q bf16 hi/lo planes (scale in f32 before split = bit-identical)
              float sc = (tt < L_) ? SCALE_ : ws_ro[O_EFF + b];
              float x = val * sc;
              ushort_t* QH = (ushort_t*)(wsw + O_Q);
              ushort_t hh = f2bf_rne(x);
              QH[pidx] = hh;
              (QH + QSZ)[pidx] = f2bf_rne(x - __uint_as_float((unsigned)hh << 16));
            } else {
              ushort_t* KH = (ushort_t*)(wsw + O_XIN2);
              ushort_t hh = f2bf_rne(val);
              KH[pidx] = hh;
              (KH + QSZ)[pidx] = f2bf_rne(val - __uint_as_float((unsigned)hh << 16));
            }
          }
        } else if (EPI == 1) {
          float g = e[1024 + cg];
          float res = is_txt ? txt[((size_t)b * L_ + tt) * D_ + cg]
                             : img[((size_t)b * N_ + (tt - L_)) * D_ + cg];
          wsw[O_X2 + (size_t)rg * D_ + cg] = res + g * val;
        } else if (EPI == 2) {
          float x = val + bias[cg];
          float z = 0.7978845608028654f * (x + 0.044715f * x * x * x);
          z = fminf(fmaxf(z, -40.f), 40.f);
          float u = __expf(-2.f * z);
          float th = (1.f - u) / (1.f + u);
          float hv = 0.5f * x * (1.f + th);
          ushort_t hh = f2bf_rne(hv);
          Hph[(size_t)rg * FF_ + cg] = hh;
          Hpl[(size_t)rg * FF_ + cg] = f2bf_rne(hv - __uint_as_float((unsigned)hh << 16));
        } else {
          float g = e[2560 + cg];
          float v2 = ws_ro[O_X2 + (size_t)rg * D_ + cg] + g * (val + bias[cg]);
          size_t oi = is_txt ? ((size_t)b * L_ + tt) * D_ + cg
                             : (size_t)B_ * L_ * D_ + ((size_t)b * N_ + (tt - L_)) * D_ + cg;
          outf[oi] = v2;
        }
      }
    }
  }
}

// ---------------- stage1: V transpose + Wmlp split (prep fused into QKV epilogue) ----------------
__global__ __launch_bounds__(256) void k_stage1(
    float* __restrict__ ws,
    const float* __restrict__ pw_t, const float* __restrict__ pw_i,
    const float* __restrict__ f1_t, const float* __restrict__ f1_i,
    const float* __restrict__ f2_t, const float* __restrict__ f2_i) {
  int blk = blockIdx.x;
  if (blk < 320) {
    // ---- V f32 [bh][t][128] -> Vt bf16 [bh][d][T] (tiled transpose) ----
    int bh = blk & 7;
    int tt = blk >> 3;      // 0..39
    int t0 = tt * 64;
    __shared__ ushort_t vls[128 * 72];
    int tid = threadIdx.x;
    {
      int tr = tid & 63, dc = tid >> 6;  // dc: 0..3 (32-d chunk)
      const float4* src = (const float4*)(ws + O_V + ((size_t)bh * T_ + t0 + tr) * HD_ + dc * 32);
      #pragma unroll
      for (int f = 0; f < 8; ++f) {
        float4 v = src[f];
        int d = dc * 32 + f * 4;
        vls[(d + 0) * 72 + tr] = f2bf_rne(v.x);
        vls[(d + 1) * 72 + tr] = f2bf_rne(v.y);
        vls[(d + 2) * 72 + tr] = f2bf_rne(v.z);
        vls[(d + 3) * 72 + tr] = f2bf_rne(v.w);
      }
    }
    __syncthreads();
    {
      int d = tid >> 1, th = (tid & 1) * 32;
      unsigned* Vt32 = (unsigned*)(ws + O_X2);
      size_t obase = (((size_t)bh * HD_ + d) * T_ + t0 + th) >> 1;
      #pragma unroll
      for (int k = 0; k < 16; ++k) {
        unsigned lo = vls[d * 72 + th + 2 * k];
        unsigned hi = vls[d * 72 + th + 2 * k + 1];
        Vt32[obase + k] = lo | (hi << 16);
      }
    }
  } else {
    // ---- Wproj/Wfc1/Wfc2 f32 -> bf16 hi planes (into O_XN region, dead after QKV) ----
    int g = (blk - 320) * 256 + threadIdx.x;  // 0..1,179,647 float4-groups
    const float* src; int local;
    if (g < 65536)        { src = pw_t; local = g; }
    else if (g < 131072)  { src = pw_i; local = g - 65536; }
    else if (g < 393216)  { src = f1_t; local = g - 131072; }
    else if (g < 655360)  { src = f1_i; local = g - 393216; }
    else if (g < 917504)  { src = f2_t; local = g - 655360; }
    else                  { src = f2_i; local = g - 917504; }
    float4 v = ((const float4*)src)[local];
    ushort4 hh;
    hh.x = f2bf_rne(v.x); hh.y = f2bf_rne(v.y); hh.z = f2bf_rne(v.z); hh.w = f2bf_rne(v.w);
    ushort_t* Wm = (ushort_t*)(ws + O_XN);
    *(ushort4*)&Wm[(size_t)g * 4] = hh;
  }
}

// ---------------- MFMA flash attention v12: Q from pre-split planes + NT partial-O stores ----------------
// grid = 3 ks x 40 qg x 8 bh = 960 blocks, 256 thr (4 waves x 16 q-rows each).
// vs v10: (1) Q frags load directly from pre-scaled bf16 hi/lo planes (conversion moved to
// QKV epilogue — bit-identical, removes 3x-redundant per-block cvt chain, halves Q bytes);
// (2) partial-O and (m,l) stores are NON-TEMPORAL — 31 MB of once-read stream no longer
// evicts the K/V/Q working set from the per-XCD L2s.
__global__ __launch_bounds__(256) void k_attn12(const float* __restrict__ ws_ro, float* __restrict__ wsw) {
  int bh = blockIdx.x & 7;            // bh-per-XCD swizzle for L2 locality
  int rest = blockIdx.x >> 3;
  int qg = rest % 40;
  int ks = rest / 40;                 // 0..2
  int kt0 = (ks == 0) ? 0 : (ks == 1) ? 14 : 27;
  int kt1 = (ks == 0) ? 14 : (ks == 1) ? 27 : 40;
  int tid = threadIdx.x;
  int w = tid >> 6, lane = tid & 63, quad = lane >> 4, lc = lane & 15;
  int q0 = (qg * 4 + w) * 16;

  const ushort_t* Qhs = (const ushort_t*)(ws_ro + O_Q);
  const ushort_t* Qls = Qhs + QSZ;
  const ushort_t* Khs = (const ushort_t*)(ws_ro + O_XIN2);
  const ushort_t* Kls = Khs + QSZ;
  const ushort_t* Vts = (const ushort_t*)(ws_ro + O_X2) + (size_t)bh * HD_ * T_;

  __shared__ __align__(16) ushort_t ksh[64 * 128];   // linear, slot-swizzled
  __shared__ __align__(16) ushort_t ksl[64 * 128];
  __shared__ __align__(16) ushort_t ps[4 * 16 * 72];
  ushort_t* pw = &ps[w * 1152];

  // staging geometry: wave w stages rows w*16..w*16+15 in 4 issues of 4 rows (64 lanes x 16B).
  int rloc = lane >> 4;            // 0..3
  int sst  = lane & 15;            // stored slot

  // ---- Q frags from pre-scaled bf16 hi/lo planes (pure loads) ----
  bf16x8 qh[4], ql[4];
  {
    size_t qbase = ((size_t)bh * T_ + q0 + lc) * HD_ + quad * 8;
    #pragma unroll
    for (int k2 = 0; k2 < 4; ++k2) {
      qh[k2] = *(const bf16x8*)&Qhs[qbase + k2 * 32];
      ql[k2] = *(const bf16x8*)&Qls[qbase + k2 * 32];
    }
  }

  f32x4 o[8];
  #pragma unroll
  for (int i = 0; i < 8; ++i) o[i] = f32x4{0.f, 0.f, 0.f, 0.f};
  float m_r[4] = {-1e30f, -1e30f, -1e30f, -1e30f};
  float l_r[4] = {0.f, 0.f, 0.f, 0.f};

  // ---- prologue: stage first K tile (async DMA), then barrier (drains vmcnt) ----
  {
    size_t gRow = (size_t)bh * T_ + kt0 * 64;
    #pragma unroll
    for (int j = 0; j < 4; ++j) {
      int r0 = w * 16 + j * 4;
      int lslot = sst ^ (j * 4 + rloc);           // (row&15) = j*4+rloc
      size_t goff = (gRow + r0 + rloc) * HD_ + (size_t)lslot * 8;
      gload_lds16(Khs + goff, &ksh[r0 * 128]);
      gload_lds16(Kls + goff, &ksl[r0 * 128]);
    }
  }
  __syncthreads();

  for (int kt = kt0; kt < kt1; ++kt) {
    // ---- S = Q K^T (3-term hi/lo), 4 x 16-key n-tiles; swizzled ds_read ----
    f32x4 s[4];
    #pragma unroll
    for (int nt = 0; nt < 4; ++nt) s[nt] = f32x4{0.f, 0.f, 0.f, 0.f};
    #pragma unroll
    for (int k2 = 0; k2 < 4; ++k2) {
      #pragma unroll
      for (int nt = 0; nt < 4; ++nt) {
        int row = nt * 16 + lc;
        int so = ((k2 * 4 + quad) ^ lc) * 8;      // stored slot = logical ^ (row&15)=lc
        bf16x8 kh = *(const bf16x8*)&ksh[row * 128 + so];
        bf16x8 kl = *(const bf16x8*)&ksl[row * 128 + so];
        s[nt] = __builtin_amdgcn_mfma_f32_16x16x32_bf16(ql[k2], kh, s[nt], 0, 0, 0);
        s[nt] = __builtin_amdgcn_mfma_f32_16x16x32_bf16(qh[k2], kl, s[nt], 0, 0, 0);
        s[nt] = __builtin_amdgcn_mfma_f32_16x16x32_bf16(qh[k2], kh, s[nt], 0, 0, 0);
      }
    }
    // all waves done reading K tile -> safe to DMA next tile into the same buffer
    __syncthreads();

    // ---- issue async DMA for tile kt+1 (overlaps with everything below) ----
    if (kt + 1 < kt1) {
      size_t gRow = (size_t)bh * T_ + (kt + 1) * 64;
      #pragma unroll
      for (int j = 0; j < 4; ++j) {
        int r0 = w * 16 + j * 4;
        int lslot = sst ^ (j * 4 + rloc);
        size_t goff = (gRow + r0 + rloc) * HD_ + (size_t)lslot * 8;
        gload_lds16(Khs + goff, &ksh[r0 * 128]);
        gload_lds16(Kls + goff, &ksl[r0 * 128]);
      }
    }

    // ---- V frags batch 0 (keys 0-31) ----
    const ushort_t* Vb = Vts + kt * 64;
    bf16x8 vb0[8];
    #pragma unroll
    for (int dt = 0; dt < 8; ++dt)
      vb0[dt] = *(const bf16x8*)&Vb[(size_t)(dt * 16 + lc) * T_ + quad * 8];

    // ---- online softmax over 64 keys ----
    float alpha[4];
    #pragma unroll
    for (int r = 0; r < 4; ++r) {
      float rm = fmaxf(fmaxf(s[0][r], s[1][r]), fmaxf(s[2][r], s[3][r]));
      rm = fmaxf(rm, __shfl_xor(rm, 1, 64));
      rm = fmaxf(rm, __shfl_xor(rm, 2, 64));
      rm = fmaxf(rm, __shfl_xor(rm, 4, 64));
      rm = fmaxf(rm, __shfl_xor(rm, 8, 64));
      float mn = fmaxf(m_r[r], rm);
      alpha[r] = __expf(m_r[r] - mn);
      m_r[r] = mn;
      float p0 = __expf(s[0][r] - mn);
      float p1 = __expf(s[1][r] - mn);
      float p2 = __expf(s[2][r] - mn);
      float p3 = __expf(s[3][r] - mn);
      float rs = (p0 + p1) + (p2 + p3);
      rs += __shfl_xor(rs, 1, 64);
      rs += __shfl_xor(rs, 2, 64);
      rs += __shfl_xor(rs, 4, 64);
      rs += __shfl_xor(rs, 8, 64);
      l_r[r] = l_r[r] * alpha[r] + rs;
      int prow = quad * 4 + r;
      pw[prow * 72 + lc]      = f2bf_rne(p0);
      pw[prow * 72 + lc + 16] = f2bf_rne(p1);
      pw[prow * 72 + lc + 32] = f2bf_rne(p2);
      pw[prow * 72 + lc + 48] = f2bf_rne(p3);
    }
    #pragma unroll
    for (int dt = 0; dt < 8; ++dt) {
      #pragma unroll
      for (int r = 0; r < 4; ++r) o[dt][r] *= alpha[r];
    }

    // ---- V frags batch 1 (keys 32-63) ----
    bf16x8 vb1[8];
    #pragma unroll
    for (int dt = 0; dt < 8; ++dt)
      vb1[dt] = *(const bf16x8*)&Vb[(size_t)(dt * 16 + lc) * T_ + 32 + quad * 8];

    // ---- P relayout (wave-private LDS, no barrier) + O += P V ----
    bf16x8 pa0 = *(const bf16x8*)&pw[lc * 72 + quad * 8];
    bf16x8 pa1 = *(const bf16x8*)&pw[lc * 72 + 32 + quad * 8];
    #pragma unroll
    for (int dt = 0; dt < 8; ++dt)
      o[dt] = __builtin_amdgcn_mfma_f32_16x16x32_bf16(pa0, vb0[dt], o[dt], 0, 0, 0);
    #pragma unroll
    for (int dt = 0; dt < 8; ++dt)
      o[dt] = __builtin_amdgcn_mfma_f32_16x16x32_bf16(pa1, vb1[dt], o[dt], 0, 0, 0);
    // drains own vmcnt (incl. DMA) + block barrier -> next tile's K visible to all waves
    __syncthreads();
  }

  // ---- write UNNORMALIZED partial O (f32) + per-row (m,l) — NON-TEMPORAL (once-read) ----
  float* OP = wsw + ((ks == 0) ? O_K : (ks == 1) ? O_V : O_ATTN);
  float* ML = wsw + O_ML;
  int trow0 = q0 + quad * 4;
  #pragma unroll
  for (int r = 0; r < 4; ++r) {
    size_t base = ((size_t)bh * T_ + (trow0 + r)) * HD_ + lc;
    #pragma unroll
    for (int dt = 0; dt < 8; ++dt)
      __builtin_nontemporal_store(o[dt][r], &OP[base + dt * 16]);
    if (lc == 0) {
      size_t mi = (((size_t)ks * 8 + bh) * T_ + (trow0 + r)) * 2;
      __builtin_nontemporal_store(m_r[r], &ML[mi]);
      __builtin_nontemporal_store(l_r[r], &ML[mi + 1]);
    }
  }
}

// ---------------- combine K-split partials -> bf16 hi/lo attn planes (at O_Q) ----------------
// grid = 40 qg x 8 bh = 320 blocks; each handles 64 q-rows x 128 d for one bh.
__global__ __launch_bounds__(256) void k_comb(const float* __restrict__ ws_ro, float* __restrict__ wsw) {
  int bh = blockIdx.x & 7;
  int qg = blockIdx.x >> 3;           // 0..39
  int b = bh >> 2, h = bh & 3;
  int q0 = qg * 64;
  int tid = threadIdx.x;
  __shared__ float wls[64][4];        // w0*inv, w1*inv, w2*inv per row
  if (tid < 64) {
    const float* ML = ws_ro + O_ML;
    size_t r0 = ((size_t)0 * 8 + bh) * T_ + q0 + tid;
    size_t r1 = ((size_t)1 * 8 + bh) * T_ + q0 + tid;
    size_t r2 = ((size_t)2 * 8 + bh) * T_ + q0 + tid;
    float m0 = ML[r0 * 2], l0 = ML[r0 * 2 + 1];
    float m1 = ML[r1 * 2], l1 = ML[r1 * 2 + 1];
    float m2 = ML[r2 * 2], l2 = ML[r2 * 2 + 1];
    float mm = fmaxf(fmaxf(m0, m1), m2);
    float w0 = __expf(m0 - mm), w1 = __expf(m1 - mm), w2 = __expf(m2 - mm);
    float inv = 1.0f / (w0 * l0 + w1 * l1 + w2 * l2);
    wls[tid][0] = w0 * inv; wls[tid][1] = w1 * inv; wls[tid][2] = w2 * inv; wls[tid][3] = 0.f;
  }
  __syncthreads();
  const float* P0 = ws_ro + O_K;
  const float* P1 = ws_ro + O_V;
  const float* P2 = ws_ro + O_ATTN;
  ushort_t* ATh = (ushort_t*)(wsw + O_Q);
  ushort_t* ATl = ATh + QSZ;
  #pragma unroll
  for (int it = 0; it < 8; ++it) {
    int idx = it * 256 + tid;          // 2048 float4-groups = 64 rows x 32
    int row = idx >> 5;
    int d4 = (idx & 31) * 4;
    size_t pb = ((size_t)bh * T_ + q0 + row) * HD_ + d4;
    float4 a = *(const float4*)&P0[pb];
    float4 c = *(const float4*)&P1[pb];
    float4 d = *(const float4*)&P2[pb];
    float w0 = wls[row][0], w1 = wls[row][1], w2 = wls[row][2];
    float v[4] = {a.x * w0 + c.x * w1 + d.x * w2,
                  a.y * w0 + c.y * w1 + d.y * w2,
                  a.z * w0 + c.z * w1 + d.z * w2,
                  a.w * w0 + c.w * w1 + d.w * w2};
    ushort4 hh, ll;
    ushort_t* hp = (ushort_t*)&hh; ushort_t* lp = (ushort_t*)&ll;
    #pragma unroll
    for (int j = 0; j < 4; ++j) {
      ushort_t hv = f2bf_rne(v[j]);
      hp[j] = hv;
      lp[j] = f2bf_rne(v[j] - __uint_as_float((unsigned)hv << 16));
    }
    size_t ob = ((size_t)b * T_ + q0 + row) * D_ + h * HD_ + d4;
    *(ushort4*)&ATh[ob] = hh;
    *(ushort4*)&ATl[ob] = ll;
  }
}

extern "C" void kernel_launch(void* const* d_in, const int* in_sizes, int n_in,
                              void* d_out, int out_size, void* d_ws, size_t ws_size,
                              hipStream_t stream) {
  (void)in_sizes; (void)n_in; (void)out_size; (void)ws_size;
  const float* txt    = (const float*)d_in[0];
  const float* img    = (const float*)d_in[1];
  const float* vec    = (const float*)d_in[2];
  const float* rope   = (const float*)d_in[3];
  const float* stemp  = (const float*)d_in[4];
  const float* sspat  = (const float*)d_in[5];
  const float* i_aw   = (const float*)d_in[6];
  const float* i_ab   = (const float*)d_in[7];
  const float* i_anw  = (const float*)d_in[8];
  const float* t_aw   = (const float*)d_in[9];
  const float* t_ab   = (const float*)d_in[10];
  const float* t_anw  = (const float*)d_in[11];
  const float* t_qkvw = (const float*)d_in[12];
  const float* i_qkvw = (const float*)d_in[13];
  const float* t_outw = (const float*)d_in[14];
  const float* i_outw = (const float*)d_in[15];
  const float* modw   = (const float*)d_in[16];
  const float* modb   = (const float*)d_in[17];
  const float* i_n2w  = (const float*)d_in[18];
  const float* t_n2w  = (const float*)d_in[19];
  const float* i_f1w  = (const float*)d_in[20];
  const float* i_f1b  = (const float*)d_in[21];
  const float* i_f2w  = (const float*)d_in[22];
  const float* i_f2b  = (const float*)d_in[23];
  const float* t_f1w  = (const float*)d_in[24];
  const float* t_f1b  = (const float*)d_in[25];
  const float* t_f2w  = (const float*)d_in[26];
  const float* t_f2b  = (const float*)d_in[27];
  float* ws = (float*)d_ws;
  float* out = (float*)d_out;
  ushort_t* XNh  = (ushort_t*)(ws + O_XN);   ushort_t* XNl  = XNh + QSZ;
  ushort_t* XI2h = (ushort_t*)(ws + O_XIN2); ushort_t* XI2l = XI2h + QSZ;
  ushort_t* Hh   = (ushort_t*)(ws + O_H);    ushort_t* Hl   = Hh + 4 * QSZ;
  // Attn output planes live at O_Q (Q planes dead after k_attn12; fc1's H overwrites later).
  ushort_t* ATh  = (ushort_t*)(ws + O_Q);    ushort_t* ATl  = ATh + QSZ;
  // Weight planes (reuse dead regions; see aliasing audit in header comments)
  ushort_t* Wqh = (ushort_t*)(ws + O_ATTN);  ushort_t* Wql = Wqh + WQ_TOTAL;
  ushort_t* Wm  = (ushort_t*)(ws + O_XN);

  // stage0: adaln(48) + mod(64) + Wqkv split(1536) — all input-only deps
  hipLaunchKernelGGL(k_stage0, dim3(48 + 64 + 1536), dim3(256), 0, stream,
                     vec, t_aw, t_ab, i_aw, i_ab, sspat, modw, modb, stemp,
                     t_qkvw, i_qkvw, ws);
  hipLaunchKernelGGL((k_rmsmod<true>), dim3(MROWS), dim3(256), 0, stream,
                     txt, img, (const float*)nullptr, t_anw, i_anw, 0, 512, ws, XNh, XNl);
  // QKV: MTILE=64 -> 960 blocks, 3-term, K=512. Fused epilogue: rope+mod,
  // Q pre-scaled bf16 hi/lo planes -> O_Q, K bf16 hi/lo planes -> O_XIN2, V f32.
  hipLaunchKernelGGL((k_gemm<64, 128, 3, 512, 12, 0>), dim3(80 * 12), dim3(256), 0, stream,
                     XNh, XNl, Wqh, Wql, Wqh + WQ_STREAM, Wql + WQ_STREAM,
                     rope, nullptr, ws, ws, txt, img,
                     (ushort_t*)nullptr, (ushort_t*)nullptr, nullptr);
  // stage1: vt(320) + Wmlp split(4608)
  hipLaunchKernelGGL(k_stage1, dim3(320 + 4608), dim3(256), 0, stream,
                     ws, t_outw, i_outw, t_f1w, i_f1w, t_f2w, i_f2w);
  // attn partials: 3-way K-split, Q planes + NT partial stores
  hipLaunchKernelGGL(k_attn12, dim3(960), dim3(256), 0, stream, ws, ws);
  // combine partials -> attn planes at O_Q
  hipLaunchKernelGGL(k_comb, dim3(320), dim3(256), 0, stream, ws, ws);
  // proj: MTILE=64 -> 640 blocks, 2-term, K=512
  hipLaunchKernelGGL((k_gemm<64, 64, 2, 512, 8, 1>), dim3(80 * 8), dim3(256), 0, stream,
                     ATh, ATl, Wm + WM_PROJ, nullptr, Wm + WM_PROJ + WM_PROJ_S, nullptr,
                     nullptr, nullptr, ws, ws, txt, img,
                     (ushort_t*)nullptr, (ushort_t*)nullptr, nullptr);
  hipLaunchKernelGGL((k_rmsmod<false>), dim3(MROWS), dim3(256), 0, stream,
                     (const float*)nullptr, (const float*)nullptr, ws + O_X2, t_n2w, i_n2w,
                     1536, 2048, ws, XI2h, XI2l);
  // fc1: MTILE=64 -> 1280 blocks, 2-term, K=512
  hipLaunchKernelGGL((k_gemm<64, 128, 2, 512, 16, 2>), dim3(80 * 16), dim3(256), 0, stream,
                     XI2h, XI2l, Wm + WM_FC1, nullptr, Wm + WM_FC1 + WM_FC1_S, nullptr,
                     t_f1b, i_f1b, ws, ws, txt, img, Hh, Hl, nullptr);
  // fc2: MTILE=64 -> 640 blocks, 2-term, K=2048
  hipLaunchKernelGGL((k_gemm<64, 64, 2, 2048, 8, 3>), dim3(80 * 8), dim3(256), 0, stream,
                     Hh, Hl, Wm + WM_FC2, nullptr, Wm + WM_FC2 + WM_FC2_S, nullptr,
                     t_f2b, i_f2b, ws, ws, txt, img,
                     (ushort_t*)nullptr, (ushort_t*)nullptr, out);
}

// Round 12
// 465.276 us; speedup vs baseline: 1.0059x; 1.0059x over previous
//
#include <hip/hip_runtime.h>
#include <math.h>

typedef unsigned short ushort_t;

// Problem constants (fixed shapes from setup_inputs)
constexpr int B_  = 2;
constexpr int L_  = 512;    // txt tokens
constexpr int N_  = 2048;   // img tokens (H=64, W=32)
constexpr int T_  = 2560;   // L_+N_
constexpr int D_  = 512;
constexpr int NH_ = 4;
constexpr int HD_ = 128;
constexpr int FF_ = 2048;
constexpr int SIXD = 3072;
constexpr int MROWS = B_ * T_;   // 5120
#define SCALE_ 0.08838834764831843f

// Workspace layout (floats). Activations stored as separate bf16 hi/lo planes.
constexpr size_t QSZ    = (size_t)B_ * NH_ * T_ * HD_;      // 2,621,440 (== B*T*D)
constexpr size_t O_ETXT = 0;
constexpr size_t O_EIMG = O_ETXT + (size_t)B_ * SIXD;       // 6144
constexpr size_t O_MOD  = O_EIMG + (size_t)B_ * SIXD;       // 12288
constexpr size_t O_EFF  = O_MOD + (size_t)B_ * NH_ * N_;    // 28672
constexpr size_t O_XN   = O_EFF + 16;                        // xn planes (hi|lo) -> later Wmlp planes
constexpr size_t O_Q    = O_XN + QSZ;                        // Q bf16 hi/lo planes (pre-scaled, roped); AT planes after comb
constexpr size_t O_K    = O_Q + QSZ;                         // attn partial O (ks=0)
constexpr size_t O_V    = O_K + QSZ;                         // f32 V; attn partial O (ks=1) during attn
constexpr size_t O_ATTN = O_V + QSZ;                         // Wqkv planes; attn partial O (ks=2)
constexpr size_t O_X2   = O_ATTN + QSZ;                      // f32 X2 (after proj); Vt bf16 during attn
constexpr size_t O_XIN2 = O_X2 + QSZ;                        // Kh/Kl planes (from QKV epi); xin2 planes later
constexpr size_t O_H    = O_Q;   // H planes (hi|lo, 4*QSZ ushorts each) over Q..ATTN span
constexpr size_t O_ML   = O_X2 + QSZ / 2;                    // (m,l) per [ks][bh][row], after Vt

// Weight plane geometry (ushort offsets)
constexpr size_t WQ_STREAM = (size_t)SIXD / 2 * D_;          // 1536*512 = 786432
constexpr size_t WQ_TOTAL  = 2 * WQ_STREAM;                  // 1,572,864 (hi plane size)
constexpr size_t WM_PROJ   = 0;                              // proj: 2 x 512*512
constexpr size_t WM_PROJ_S = (size_t)D_ * D_;                // 262144
constexpr size_t WM_FC1    = WM_PROJ + 2 * WM_PROJ_S;        // 524288
constexpr size_t WM_FC1_S  = (size_t)FF_ * D_;               // 1048576
constexpr size_t WM_FC2    = WM_FC1 + 2 * WM_FC1_S;          // 2621440
constexpr size_t WM_FC2_S  = (size_t)D_ * FF_;               // 1048576

typedef short bf16x8 __attribute__((ext_vector_type(8)));
typedef float f32x4 __attribute__((ext_vector_type(4)));

__device__ __forceinline__ ushort_t f2bf_rne(float x) {
  unsigned u = __float_as_uint(x);
  u += 0x7fff + ((u >> 16) & 1);
  return (ushort_t)(u >> 16);
}

// async global->LDS, 16B per lane; LDS dest = wave-uniform base + lane*16 (HW rule)
__device__ __forceinline__ void gload_lds16(const ushort_t* g, ushort_t* l) {
  __builtin_amdgcn_global_load_lds(
      (const __attribute__((address_space(1))) void*)g,
      (__attribute__((address_space(3))) void*)l, 16, 0, 0);
}

// ---------------- stage0: adaln + mod/eff + Wqkv hi/lo split (all input-only deps) ----------------
__global__ __launch_bounds__(256) void k_stage0(
    const float* __restrict__ vec,
    const float* __restrict__ wt, const float* __restrict__ bt,
    const float* __restrict__ wi, const float* __restrict__ bi,
    const float* __restrict__ sspat, const float* __restrict__ mw,
    const float* __restrict__ mb, const float* __restrict__ stemp,
    const float* __restrict__ qkvwt, const float* __restrict__ qkvwi,
    float* __restrict__ ws) {
  int blk = blockIdx.x;
  if (blk < 48) {
    // ---- adaLN: e = silu(vec) @ W.T + b ----
    int s = blk / 24;
    int rem = blk % 24;
    int b = rem / 12;
    int o = (rem % 12) * 256 + threadIdx.x;
    __shared__ float sv[D_];
    for (int i = threadIdx.x; i < D_; i += 256) {
      float x = vec[b * D_ + i];
      sv[i] = x / (1.0f + __expf(-x));
    }
    __syncthreads();
    const float* w = (s == 0) ? wt : wi;
    const float* bb = (s == 0) ? bt : bi;
    const float4* wrow = (const float4*)(w + (size_t)o * D_);
    float acc = 0.f;
    for (int d4 = 0; d4 < D_ / 4; ++d4) {
      float4 wv = wrow[d4];
      int d = d4 * 4;
      acc += wv.x * sv[d] + wv.y * sv[d + 1] + wv.z * sv[d + 2] + wv.w * sv[d + 3];
    }
    acc += bb[o];
    float* e = ws + ((s == 0) ? O_ETXT : O_EIMG);
    e[b * SIXD + o] = acc;
  } else if (blk < 112) {
    // ---- mod (bilinear upsample + affine + clip + exp) and eff ----
    int idx = (blk - 48) * 256 + threadIdx.x;  // B*NH*N = 16384
    if (idx < B_) {
      float s = 0.f;
      for (int h = 0; h < NH_; ++h) s += stemp[idx * NH_ + h];
      float t = fmaxf(s * 0.25f, 0.1f);
      ws[O_EFF + idx] = SCALE_ / t;
    }
    int b = idx / (NH_ * N_);
    int h = (idx / N_) % NH_;
    int n = idx % N_;
    int y = n >> 5;      // W=32
    int x = n & 31;
    float fy = (y + 0.5f) * 0.125f - 0.5f;
    float fx = (x + 0.5f) * 0.25f  - 0.5f;
    float y0f = floorf(fy), x0f = floorf(fx);
    float wy = fy - y0f, wx = fx - x0f;
    int y0 = (int)y0f, x0 = (int)x0f;
    int iy0 = y0 < 0 ? 0 : y0, iy1 = (y0 + 1) > 7 ? 7 : (y0 + 1);
    int ix0 = x0 < 0 ? 0 : x0, ix1 = (x0 + 1) > 7 ? 7 : (x0 + 1);
    const float* S = sspat + b * 64;
    float v00 = S[iy0*8+ix0], v01 = S[iy0*8+ix1];
    float v10 = S[iy1*8+ix0], v11 = S[iy1*8+ix1];
    float up = (1.f-wy)*((1.f-wx)*v00 + wx*v01) + wy*((1.f-wx)*v10 + wx*v11);
    float m = up * mw[h] + mb[h];
    m = fminf(fmaxf(m, -2.f), 2.f);
    ws[O_MOD + idx] = __expf(m);
  } else {
    // ---- Wqkv f32 -> bf16 hi/lo planes (into O_ATTN region, dead until attn) ----
    int g = (blk - 112) * 256 + threadIdx.x;   // 0 .. 393215 float4-groups
    int s = g >= (int)(WQ_STREAM / 4);
    const float4* src = (const float4*)(s ? qkvwi : qkvwt);
    float4 v = src[g - s * (int)(WQ_STREAM / 4)];
    ushort4 hh, ll;
    hh.x = f2bf_rne(v.x); hh.y = f2bf_rne(v.y); hh.z = f2bf_rne(v.z); hh.w = f2bf_rne(v.w);
    ll.x = f2bf_rne(v.x - __uint_as_float((unsigned)hh.x << 16));
    ll.y = f2bf_rne(v.y - __uint_as_float((unsigned)hh.y << 16));
    ll.z = f2bf_rne(v.z - __uint_as_float((unsigned)hh.z << 16));
    ll.w = f2bf_rne(v.w - __uint_as_float((unsigned)hh.w << 16));
    ushort_t* Wqh = (ushort_t*)(ws + O_ATTN);
    ushort_t* Wql = Wqh + WQ_TOTAL;
    *(ushort4*)&Wqh[(size_t)g * 4] = hh;
    *(ushort4*)&Wql[(size_t)g * 4] = ll;
  }
}

// ---------------- rms + adaLN modulate -> bf16 hi/lo planes ----------------
template<bool FROM_INPUT>
__global__ __launch_bounds__(256) void k_rmsmod(const float* __restrict__ txt, const float* __restrict__ img,
                                                const float* __restrict__ src_ws,
                                                const float* __restrict__ nw_txt, const float* __restrict__ nw_img,
                                                int sh_off, int sc_off,
                                                const float* __restrict__ e_ws,
                                                ushort_t* __restrict__ oh, ushort_t* __restrict__ ol) {
  int row = blockIdx.x;         // B*T rows
  int b = row / T_;
  int t = row % T_;
  bool is_txt = t < L_;
  int i0 = threadIdx.x * 2;
  float x0, x1;
  if (FROM_INPUT) {
    const float* src = is_txt ? (txt + ((size_t)b * L_ + t) * D_)
                              : (img + ((size_t)b * N_ + (t - L_)) * D_);
    x0 = src[i0]; x1 = src[i0 + 1];
  } else {
    const float* src = src_ws + (size_t)row * D_;
    x0 = src[i0]; x1 = src[i0 + 1];
  }
  float ss = x0 * x0 + x1 * x1;
  for (int off = 32; off; off >>= 1) ss += __shfl_down(ss, off, 64);
  __shared__ float red[4];
  if ((threadIdx.x & 63) == 0) red[threadIdx.x >> 6] = ss;
  __syncthreads();
  float tot = red[0] + red[1] + red[2] + red[3];
  float r = rsqrtf(tot * (1.0f / D_) + 1e-6f);
  const float* e = e_ws + (is_txt ? O_ETXT : O_EIMG) + (size_t)b * SIXD;
  const float* nw = is_txt ? nw_txt : nw_img;
  float y0 = x0 * r * nw[i0]     * (1.f + e[sc_off + i0])     + e[sh_off + i0];
  float y1 = x1 * r * nw[i0 + 1] * (1.f + e[sc_off + i0 + 1]) + e[sh_off + i0 + 1];
  ushort_t h0 = f2bf_rne(y0), h1 = f2bf_rne(y1);
  ushort_t l0 = f2bf_rne(y0 - __uint_as_float((unsigned)h0 << 16));
  ushort_t l1 = f2bf_rne(y1 - __uint_as_float((unsigned)h1 << 16));
  *(unsigned*)&oh[(size_t)row * D_ + i0] = (unsigned)h0 | ((unsigned)h1 << 16);
  *(unsigned*)&ol[(size_t)row * D_ + i0] = (unsigned)l0 | ((unsigned)l1 << 16);
}

// ---------------- templated MFMA GEMM: single-buffered gl_lds staging, MTILE param ----------------
// EPI: 0 = QKV fused epilogue: rope+mod via __shfl_xor(1); Q pre-SCALED bf16 hi/lo planes ->
//          O_Q, K bf16 hi/lo planes -> O_XIN2, V f32. biast = rope table.
//      1 = proj gate+residual->X2,  2 = fc1 bias+gelu->H planes,  3 = fc2 bias+gate+residual->out
template<int MTILE, int NTILE, int NTERMS, int KDIM, int NPR, int EPI>
__global__ __launch_bounds__(256) void k_gemm(
    const ushort_t* __restrict__ Aph, const ushort_t* __restrict__ Apl,
    const ushort_t* __restrict__ Wth, const ushort_t* __restrict__ Wtl,
    const ushort_t* __restrict__ Wih, const ushort_t* __restrict__ Wil,
    const float* __restrict__ biast, const float* __restrict__ biasi,
    const float* __restrict__ ws_ro, float* __restrict__ wsw,
    const float* __restrict__ txt, const float* __restrict__ img,
    ushort_t* __restrict__ Hph, ushort_t* __restrict__ Hpl, float* __restrict__ outf) {
  int mt = blockIdx.x / NPR, nt = blockIdx.x % NPR;
  int row0 = mt * MTILE;
  int col0 = nt * NTILE;
  int b = row0 / T_;
  int t0 = row0 % T_;
  bool is_txt = t0 < L_;   // L_=512 divisible by MTILE -> tiles never straddle
  const ushort_t* Wh = is_txt ? Wth : Wih;
  const ushort_t* Wl = (NTERMS == 3) ? (is_txt ? Wtl : Wil) : nullptr;

  __shared__ __align__(16) ushort_t ash[MTILE * 32];
  __shared__ __align__(16) ushort_t asl[MTILE * 32];
  __shared__ __align__(16) ushort_t bsh[NTILE * 32];
  __shared__ __align__(16) ushort_t bsl[(NTERMS == 3) ? NTILE * 32 : 8];

  int tid = threadIdx.x;
  int w = tid >> 6, lane = tid & 63, quad = lane >> 4, lc = lane & 15;
  int rh = w >> 1, ch = w & 1;
  constexpr int NFR = NTILE / 32;
  constexpr int MR  = MTILE / 32;

  // staging lane geometry: lane l lands at LDS row chunk*16+(l>>2), stored slot l&3;
  // its global source is the LOGICAL slot (l&3)^((l>>3)&3)  [(row>>1)&3 with chunk*16≡0]
  int Rloc  = lane >> 2;
  int lslot = (lane & 3) ^ ((lane >> 3) & 3);
  // ds_read: want logical slot=quad at row ar (ar≡lc mod 16, base mult of 16)
  int ssw = (quad ^ ((lc >> 1) & 3)) * 8;

  f32x4 acc[MR][NFR];
  #pragma unroll
  for (int m = 0; m < MR; ++m)
    #pragma unroll
    for (int n = 0; n < NFR; ++n) acc[m][n] = f32x4{0.f, 0.f, 0.f, 0.f};

  for (int kt = 0; kt < KDIM / 32; ++kt) {
    int scol = kt * 32 + lslot * 8;
    // ---- stage A hi/lo: MTILE/16 chunks of 16 rows, distributed across 4 waves ----
    #pragma unroll
    for (int cc = 0; cc < MTILE / 64; ++cc) {
      int c = w * (MTILE / 64) + cc;
      size_t goff = (size_t)(row0 + c * 16 + Rloc) * KDIM + scol;
      gload_lds16(Aph + goff, &ash[c * 512]);
      gload_lds16(Apl + goff, &asl[c * 512]);
    }
    // ---- stage W: NTILE/16 chunks distributed across 4 waves ----
    #pragma unroll
    for (int cc = 0; cc < NTILE / 64; ++cc) {
      int c = w + cc * 4;
      size_t goff = (size_t)(col0 + c * 16 + Rloc) * KDIM + scol;
      gload_lds16(Wh + goff, &bsh[c * 512]);
      if (NTERMS == 3) gload_lds16(Wl + goff, &bsl[c * 512]);
    }
    __syncthreads();

    bf16x8 afh[MR], afl[MR];
    #pragma unroll
    for (int m = 0; m < MR; ++m) {
      int ar = rh * (MTILE / 2) + m * 16 + lc;
      afh[m] = *(const bf16x8*)&ash[ar * 32 + ssw];
      afl[m] = *(const bf16x8*)&asl[ar * 32 + ssw];
    }
    #pragma unroll
    for (int n = 0; n < NFR; ++n) {
      int br = ch * (NTILE / 2) + n * 16 + lc;
      bf16x8 bh = *(const bf16x8*)&bsh[br * 32 + ssw];
      if (NTERMS == 3) {
        bf16x8 bl = *(const bf16x8*)&bsl[br * 32 + ssw];
        #pragma unroll
        for (int m = 0; m < MR; ++m) {
          acc[m][n] = __builtin_amdgcn_mfma_f32_16x16x32_bf16(afl[m], bh, acc[m][n], 0, 0, 0);
          acc[m][n] = __builtin_amdgcn_mfma_f32_16x16x32_bf16(afh[m], bl, acc[m][n], 0, 0, 0);
          acc[m][n] = __builtin_amdgcn_mfma_f32_16x16x32_bf16(afh[m], bh, acc[m][n], 0, 0, 0);
        }
      } else {
        #pragma unroll
        for (int m = 0; m < MR; ++m) {
          acc[m][n] = __builtin_amdgcn_mfma_f32_16x16x32_bf16(afl[m], bh, acc[m][n], 0, 0, 0);
          acc[m][n] = __builtin_amdgcn_mfma_f32_16x16x32_bf16(afh[m], bh, acc[m][n], 0, 0, 0);
        }
      }
    }
    __syncthreads();
  }

  const float* e = ws_ro + (is_txt ? O_ETXT : O_EIMG) + (size_t)b * SIXD;
  const float* bias = is_txt ? biast : biasi;
  #pragma unroll
  for (int m = 0; m < MR; ++m) {
    #pragma unroll
    for (int n = 0; n < NFR; ++n) {
      #pragma unroll
      for (int r = 0; r < 4; ++r) {
        int rg = row0 + rh * (MTILE / 2) + m * 16 + quad * 4 + r;
        int cg = col0 + ch * (NTILE / 2) + n * 16 + lc;
        float val = acc[m][n][r];
        int tt = rg % T_;
        if (EPI == 0) {
          // fused rope+mod + Q/K/V scatter. which/h block-uniform (128-aligned col tile).
          int which = cg >> 9, h = (cg >> 7) & 3, dd = cg & 127;
          float partner = __shfl_xor(val, 1, 64);   // value at dd^1 (lane^1)
          size_t pidx = (((size_t)b * NH_ + h) * T_ + tt) * HD_ + dd;
          if (which == 2) {
            wsw[O_V + pidx] = val;
          } else {
            if (tt >= L_) {
              int nn = tt - L_;
              float c = biast[(size_t)nn * HD_ + (dd & ~1)];      // rope table via biast
              float s = biast[(size_t)nn * HD_ + (dd & ~1) + 1];
              float mm = ws_ro[O_MOD + ((size_t)b * NH_ + h) * N_ + nn];
              val = ((dd & 1) ? (val * c + partner * s)
                              : (val * c - partner * s)) * mm;
            }
            if (which == 0) {
              // pre-scaled Q bf16 hi/lo planes (scale in f32 before split = bit-identical)
              float sc = (tt < L_) ? SCALE_ : ws_ro[O_EFF + b];
              float x = val * sc;
              ushort_t* QH = (ushort_t*)(wsw + O_Q);
              ushort_t hh = f2bf_rne(x);
              QH[pidx] = hh;
              (QH + QSZ)[pidx] = f2bf_rne(x - __uint_as_float((unsigned)hh << 16));
            } else {
              ushort_t* KH = (ushort_t*)(wsw + O_XIN2);
              ushort_t hh = f2bf_rne(val);
              KH[pidx] = hh;
              (KH + QSZ)[pidx] = f2bf_rne(val - __uint_as_float((unsigned)hh << 16));
            }
          }
        } else if (EPI == 1) {
          float g = e[1024 + cg];
          float res = is_txt ? txt[((size_t)b * L_ + tt) * D_ + cg]
                             : img[((size_t)b * N_ + (tt - L_)) * D_ + cg];
          wsw[O_X2 + (size_t)rg * D_ + cg] = res + g * val;
        } else if (EPI == 2) {
          float x = val + bias[cg];
          float z = 0.7978845608028654f * (x + 0.044715f * x * x * x);
          z = fminf(fmaxf(z, -40.f), 40.f);
          float u = __expf(-2.f * z);
          float th = (1.f - u) / (1.f + u);
          float hv = 0.5f * x * (1.f + th);
          ushort_t hh = f2bf_rne(hv);
          Hph[(size_t)rg * FF_ + cg] = hh;
          Hpl[(size_t)rg * FF_ + cg] = f2bf_rne(hv - __uint_as_float((unsigned)hh << 16));
        } else {
          float g = e[2560 + cg];
          float v2 = ws_ro[O_X2 + (size_t)rg * D_ + cg] + g * (val + bias[cg]);
          size_t oi = is_txt ? ((size_t)b * L_ + tt) * D_ + cg
                             : (size_t)B_ * L_ * D_ + ((size_t)b * N_ + (tt - L_)) * D_ + cg;
          outf[oi] = v2;
        }
      }
    }
  }
}

// ---------------- stage1: V transpose + Wmlp split (prep fused into QKV epilogue) ----------------
__global__ __launch_bounds__(256) void k_stage1(
    float* __restrict__ ws,
    const float* __restrict__ pw_t, const float* __restrict__ pw_i,
    const float* __restrict__ f1_t, const float* __restrict__ f1_i,
    const float* __restrict__ f2_t, const float* __restrict__ f2_i) {
  int blk = blockIdx.x;
  if (blk < 320) {
    // ---- V f32 [bh][t][128] -> Vt bf16 [bh][d][T] (tiled transpose) ----
    int bh = blk & 7;
    int tt = blk >> 3;      // 0..39
    int t0 = tt * 64;
    __shared__ ushort_t vls[128 * 72];
    int tid = threadIdx.x;
    {
      int tr = tid & 63, dc = tid >> 6;  // dc: 0..3 (32-d chunk)
      const float4* src = (const float4*)(ws + O_V + ((size_t)bh * T_ + t0 + tr) * HD_ + dc * 32);
      #pragma unroll
      for (int f = 0; f < 8; ++f) {
        float4 v = src[f];
        int d = dc * 32 + f * 4;
        vls[(d + 0) * 72 + tr] = f2bf_rne(v.x);
        vls[(d + 1) * 72 + tr] = f2bf_rne(v.y);
        vls[(d + 2) * 72 + tr] = f2bf_rne(v.z);
        vls[(d + 3) * 72 + tr] = f2bf_rne(v.w);
      }
    }
    __syncthreads();
    {
      int d = tid >> 1, th = (tid & 1) * 32;
      unsigned* Vt32 = (unsigned*)(ws + O_X2);
      size_t obase = (((size_t)bh * HD_ + d) * T_ + t0 + th) >> 1;
      #pragma unroll
      for (int k = 0; k < 16; ++k) {
        unsigned lo = vls[d * 72 + th + 2 * k];
        unsigned hi = vls[d * 72 + th + 2 * k + 1];
        Vt32[obase + k] = lo | (hi << 16);
      }
    }
  } else {
    // ---- Wproj/Wfc1/Wfc2 f32 -> bf16 hi planes (into O_XN region, dead after QKV) ----
    int g = (blk - 320) * 256 + threadIdx.x;  // 0..1,179,647 float4-groups
    const float* src; int local;
    if (g < 65536)        { src = pw_t; local = g; }
    else if (g < 131072)  { src = pw_i; local = g - 65536; }
    else if (g < 393216)  { src = f1_t; local = g - 131072; }
    else if (g < 655360)  { src = f1_i; local = g - 393216; }
    else if (g < 917504)  { src = f2_t; local = g - 655360; }
    else                  { src = f2_i; local = g - 917504; }
    float4 v = ((const float4*)src)[local];
    ushort4 hh;
    hh.x = f2bf_rne(v.x); hh.y = f2bf_rne(v.y); hh.z = f2bf_rne(v.z); hh.w = f2bf_rne(v.w);
    ushort_t* Wm = (ushort_t*)(ws + O_XN);
    *(ushort4*)&Wm[(size_t)g * 4] = hh;
  }
}

// ---------------- MFMA flash attention v13: Q from pre-split planes, REGULAR partial stores ----------------
// grid = 3 ks x 40 qg x 8 bh = 960 blocks, 256 thr (4 waves x 16 q-rows each).
// vs v12: partial-O/(m,l) stores back to REGULAR (L2-allocating) — they are read immediately
// by k_comb, and the R11 A/B showed NT stores push them to HBM and cost comb ~12us (more
// than attn's NT gain). Q pre-split planes retained (clean win).
__global__ __launch_bounds__(256) void k_attn13(const float* __restrict__ ws_ro, float* __restrict__ wsw) {
  int bh = blockIdx.x & 7;            // bh-per-XCD swizzle for L2 locality
  int rest = blockIdx.x >> 3;
  int qg = rest % 40;
  int ks = rest / 40;                 // 0..2
  int kt0 = (ks == 0) ? 0 : (ks == 1) ? 14 : 27;
  int kt1 = (ks == 0) ? 14 : (ks == 1) ? 27 : 40;
  int tid = threadIdx.x;
  int w = tid >> 6, lane = tid & 63, quad = lane >> 4, lc = lane & 15;
  int q0 = (qg * 4 + w) * 16;

  const ushort_t* Qhs = (const ushort_t*)(ws_ro + O_Q);
  const ushort_t* Qls = Qhs + QSZ;
  const ushort_t* Khs = (const ushort_t*)(ws_ro + O_XIN2);
  const ushort_t* Kls = Khs + QSZ;
  const ushort_t* Vts = (const ushort_t*)(ws_ro + O_X2) + (size_t)bh * HD_ * T_;

  __shared__ __align__(16) ushort_t ksh[64 * 128];   // linear, slot-swizzled
  __shared__ __align__(16) ushort_t ksl[64 * 128];
  __shared__ __align__(16) ushort_t ps[4 * 16 * 72];
  ushort_t* pw = &ps[w * 1152];

  // staging geometry: wave w stages rows w*16..w*16+15 in 4 issues of 4 rows (64 lanes x 16B).
  int rloc = lane >> 4;            // 0..3
  int sst  = lane & 15;            // stored slot

  // ---- Q frags from pre-scaled bf16 hi/lo planes (pure loads) ----
  bf16x8 qh[4], ql[4];
  {
    size_t qbase = ((size_t)bh * T_ + q0 + lc) * HD_ + quad * 8;
    #pragma unroll
    for (int k2 = 0; k2 < 4; ++k2) {
      qh[k2] = *(const bf16x8*)&Qhs[qbase + k2 * 32];
      ql[k2] = *(const bf16x8*)&Qls[qbase + k2 * 32];
    }
  }

  f32x4 o[8];
  #pragma unroll
  for (int i = 0; i < 8; ++i) o[i] = f32x4{0.f, 0.f, 0.f, 0.f};
  float m_r[4] = {-1e30f, -1e30f, -1e30f, -1e30f};
  float l_r[4] = {0.f, 0.f, 0.f, 0.f};

  // ---- prologue: stage first K tile (async DMA), then barrier (drains vmcnt) ----
  {
    size_t gRow = (size_t)bh * T_ + kt0 * 64;
    #pragma unroll
    for (int j = 0; j < 4; ++j) {
      int r0 = w * 16 + j * 4;
      int lslot = sst ^ (j * 4 + rloc);           // (row&15) = j*4+rloc
      size_t goff = (gRow + r0 + rloc) * HD_ + (size_t)lslot * 8;
      gload_lds16(Khs + goff, &ksh[r0 * 128]);
      gload_lds16(Kls + goff, &ksl[r0 * 128]);
    }
  }
  __syncthreads();

  for (int kt = kt0; kt < kt1; ++kt) {
    // ---- S = Q K^T (3-term hi/lo), 4 x 16-key n-tiles; swizzled ds_read ----
    f32x4 s[4];
    #pragma unroll
    for (int nt = 0; nt < 4; ++nt) s[nt] = f32x4{0.f, 0.f, 0.f, 0.f};
    #pragma unroll
    for (int k2 = 0; k2 < 4; ++k2) {
      #pragma unroll
      for (int nt = 0; nt < 4; ++nt) {
        int row = nt * 16 + lc;
        int so = ((k2 * 4 + quad) ^ lc) * 8;      // stored slot = logical ^ (row&15)=lc
        bf16x8 kh = *(const bf16x8*)&ksh[row * 128 + so];
        bf16x8 kl = *(const bf16x8*)&ksl[row * 128 + so];
        s[nt] = __builtin_amdgcn_mfma_f32_16x16x32_bf16(ql[k2], kh, s[nt], 0, 0, 0);
        s[nt] = __builtin_amdgcn_mfma_f32_16x16x32_bf16(qh[k2], kl, s[nt], 0, 0, 0);
        s[nt] = __builtin_amdgcn_mfma_f32_16x16x32_bf16(qh[k2], kh, s[nt], 0, 0, 0);
      }
    }
    // all waves done reading K tile -> safe to DMA next tile into the same buffer
    __syncthreads();

    // ---- issue async DMA for tile kt+1 (overlaps with everything below) ----
    if (kt + 1 < kt1) {
      size_t gRow = (size_t)bh * T_ + (kt + 1) * 64;
      #pragma unroll
      for (int j = 0; j < 4; ++j) {
        int r0 = w * 16 + j * 4;
        int lslot = sst ^ (j * 4 + rloc);
        size_t goff = (gRow + r0 + rloc) * HD_ + (size_t)lslot * 8;
        gload_lds16(Khs + goff, &ksh[r0 * 128]);
        gload_lds16(Kls + goff, &ksl[r0 * 128]);
      }
    }

    // ---- V frags batch 0 (keys 0-31) ----
    const ushort_t* Vb = Vts + kt * 64;
    bf16x8 vb0[8];
    #pragma unroll
    for (int dt = 0; dt < 8; ++dt)
      vb0[dt] = *(const bf16x8*)&Vb[(size_t)(dt * 16 + lc) * T_ + quad * 8];

    // ---- online softmax over 64 keys ----
    float alpha[4];
    #pragma unroll
    for (int r = 0; r < 4; ++r) {
      float rm = fmaxf(fmaxf(s[0][r], s[1][r]), fmaxf(s[2][r], s[3][r]));
      rm = fmaxf(rm, __shfl_xor(rm, 1, 64));
      rm = fmaxf(rm, __shfl_xor(rm, 2, 64));
      rm = fmaxf(rm, __shfl_xor(rm, 4, 64));
      rm = fmaxf(rm, __shfl_xor(rm, 8, 64));
      float mn = fmaxf(m_r[r], rm);
      alpha[r] = __expf(m_r[r] - mn);
      m_r[r] = mn;
      float p0 = __expf(s[0][r] - mn);
      float p1 = __expf(s[1][r] - mn);
      float p2 = __expf(s[2][r] - mn);
      float p3 = __expf(s[3][r] - mn);
      float rs = (p0 + p1) + (p2 + p3);
      rs += __shfl_xor(rs, 1, 64);
      rs += __shfl_xor(rs, 2, 64);
      rs += __shfl_xor(rs, 4, 64);
      rs += __shfl_xor(rs, 8, 64);
      l_r[r] = l_r[r] * alpha[r] + rs;
      int prow = quad * 4 + r;
      pw[prow * 72 + lc]      = f2bf_rne(p0);
      pw[prow * 72 + lc + 16] = f2bf_rne(p1);
      pw[prow * 72 + lc + 32] = f2bf_rne(p2);
      pw[prow * 72 + lc + 48] = f2bf_rne(p3);
    }
    #pragma unroll
    for (int dt = 0; dt < 8; ++dt) {
      #pragma unroll
      for (int r = 0; r < 4; ++r) o[dt][r] *= alpha[r];
    }

    // ---- V frags batch 1 (keys 32-63) ----
    bf16x8 vb1[8];
    #pragma unroll
    for (int dt = 0; dt < 8; ++dt)
      vb1[dt] = *(const bf16x8*)&Vb[(size_t)(dt * 16 + lc) * T_ + 32 + quad * 8];

    // ---- P relayout (wave-private LDS, no barrier) + O += P V ----
    bf16x8 pa0 = *(const bf16x8*)&pw[lc * 72 + quad * 8];
    bf16x8 pa1 = *(const bf16x8*)&pw[lc * 72 + 32 + quad * 8];
    #pragma unroll
    for (int dt = 0; dt < 8; ++dt)
      o[dt] = __builtin_amdgcn_mfma_f32_16x16x32_bf16(pa0, vb0[dt], o[dt], 0, 0, 0);
    #pragma unroll
    for (int dt = 0; dt < 8; ++dt)
      o[dt] = __builtin_amdgcn_mfma_f32_16x16x32_bf16(pa1, vb1[dt], o[dt], 0, 0, 0);
    // drains own vmcnt (incl. DMA) + block barrier -> next tile's K visible to all waves
    __syncthreads();
  }

  // ---- write UNNORMALIZED partial O (f32) + per-row (m,l) — regular stores (read by k_comb) ----
  float* OP = wsw + ((ks == 0) ? O_K : (ks == 1) ? O_V : O_ATTN);
  float* ML = wsw + O_ML;
  int trow0 = q0 + quad * 4;
  #pragma unroll
  for (int r = 0; r < 4; ++r) {
    size_t base = ((size_t)bh * T_ + (trow0 + r)) * HD_ + lc;
    #pragma unroll
    for (int dt = 0; dt < 8; ++dt) OP[base + dt * 16] = o[dt][r];
    if (lc == 0) {
      size_t mi = (((size_t)ks * 8 + bh) * T_ + (trow0 + r)) * 2;
      ML[mi]     = m_r[r];
      ML[mi + 1] = l_r[r];
    }
  }
}

// ---------------- combine K-split partials -> bf16 hi/lo attn planes (at O_Q) ----------------
// grid = 40 qg x 8 bh = 320 blocks; each handles 64 q-rows x 128 d for one bh.
__global__ __launch_bounds__(256) void k_comb(const float* __restrict__ ws_ro, float* __restrict__ wsw) {
  int bh = blockIdx.x & 7;
  int qg = blockIdx.x >> 3;           // 0..39
  int b = bh >> 2, h = bh & 3;
  int q0 = qg * 64;
  int tid = threadIdx.x;
  __shared__ float wls[64][4];        // w0*inv, w1*inv, w2*inv per row
  if (tid < 64) {
    const float* ML = ws_ro + O_ML;
    size_t r0 = ((size_t)0 * 8 + bh) * T_ + q0 + tid;
    size_t r1 = ((size_t)1 * 8 + bh) * T_ + q0 + tid;
    size_t r2 = ((size_t)2 * 8 + bh) * T_ + q0 + tid;
    float m0 = ML[r0 * 2], l0 = ML[r0 * 2 + 1];
    float m1 = ML[r1 * 2], l1 = ML[r1 * 2 + 1];
    float m2 = ML[r2 * 2], l2 = ML[r2 * 2 + 1];
    float mm = fmaxf(fmaxf(m0, m1), m2);
    float w0 = __expf(m0 - mm), w1 = __expf(m1 - mm), w2 = __expf(m2 - mm);
    float inv = 1.0f / (w0 * l0 + w1 * l1 + w2 * l2);
    wls[tid][0] = w0 * inv; wls[tid][1] = w1 * inv; wls[tid][2] = w2 * inv; wls[tid][3] = 0.f;
  }
  __syncthreads();
  const float* P0 = ws_ro + O_K;
  const float* P1 = ws_ro + O_V;
  const float* P2 = ws_ro + O_ATTN;
  ushort_t* ATh = (ushort_t*)(wsw + O_Q);
  ushort_t* ATl = ATh + QSZ;
  #pragma unroll
  for (int it = 0; it < 8; ++it) {
    int idx = it * 256 + tid;          // 2048 float4-groups = 64 rows x 32
    int row = idx >> 5;
    int d4 = (idx & 31) * 4;
    size_t pb = ((size_t)bh * T_ + q0 + row) * HD_ + d4;
    float4 a = *(const float4*)&P0[pb];
    float4 c = *(const float4*)&P1[pb];
    float4 d = *(const float4*)&P2[pb];
    float w0 = wls[row][0], w1 = wls[row][1], w2 = wls[row][2];
    float v[4] = {a.x * w0 + c.x * w1 + d.x * w2,
                  a.y * w0 + c.y * w1 + d.y * w2,
                  a.z * w0 + c.z * w1 + d.z * w2,
                  a.w * w0 + c.w * w1 + d.w * w2};
    ushort4 hh, ll;
    ushort_t* hp = (ushort_t*)&hh; ushort_t* lp = (ushort_t*)&ll;
    #pragma unroll
    for (int j = 0; j < 4; ++j) {
      ushort_t hv = f2bf_rne(v[j]);
      hp[j] = hv;
      lp[j] = f2bf_rne(v[j] - __uint_as_float((unsigned)hv << 16));
    }
    size_t ob = ((size_t)b * T_ + q0 + row) * D_ + h * HD_ + d4;
    *(ushort4*)&ATh[ob] = hh;
    *(ushort4*)&ATl[ob] = ll;
  }
}

extern "C" void kernel_launch(void* const* d_in, const int* in_sizes, int n_in,
                              void* d_out, int out_size, void* d_ws, size_t ws_size,
                              hipStream_t stream) {
  (void)in_sizes; (void)n_in; (void)out_size; (void)ws_size;
  const float* txt    = (const float*)d_in[0];
  const float* img    = (const float*)d_in[1];
  const float* vec    = (const float*)d_in[2];
  const float* rope   = (const float*)d_in[3];
  const float* stemp  = (const float*)d_in[4];
  const float* sspat  = (const float*)d_in[5];
  const float* i_aw   = (const float*)d_in[6];
  const float* i_ab   = (const float*)d_in[7];
  const float* i_anw  = (const float*)d_in[8];
  const float* t_aw   = (const float*)d_in[9];
  const float* t_ab   = (const float*)d_in[10];
  const float* t_anw  = (const float*)d_in[11];
  const float* t_qkvw = (const float*)d_in[12];
  const float* i_qkvw = (const float*)d_in[13];
  const float* t_outw = (const float*)d_in[14];
  const float* i_outw = (const float*)d_in[15];
  const float* modw   = (const float*)d_in[16];
  const float* modb   = (const float*)d_in[17];
  const float* i_n2w  = (const float*)d_in[18];
  const float* t_n2w  = (const float*)d_in[19];
  const float* i_f1w  = (const float*)d_in[20];
  const float* i_f1b  = (const float*)d_in[21];
  const float* i_f2w  = (const float*)d_in[22];
  const float* i_f2b  = (const float*)d_in[23];
  const float* t_f1w  = (const float*)d_in[24];
  const float* t_f1b  = (const float*)d_in[25];
  const float* t_f2w  = (const float*)d_in[26];
  const float* t_f2b  = (const float*)d_in[27];
  float* ws = (float*)d_ws;
  float* out = (float*)d_out;
  ushort_t* XNh  = (ushort_t*)(ws + O_XN);   ushort_t* XNl  = XNh + QSZ;
  ushort_t* XI2h = (ushort_t*)(ws + O_XIN2); ushort_t* XI2l = XI2h + QSZ;
  ushort_t* Hh   = (ushort_t*)(ws + O_H);    ushort_t* Hl   = Hh + 4 * QSZ;
  // Attn output planes live at O_Q (Q planes dead after k_attn13; fc1's H overwrites later).
  ushort_t* ATh  = (ushort_t*)(ws + O_Q);    ushort_t* ATl  = ATh + QSZ;
  // Weight planes (reuse dead regions; see aliasing audit in header comments)
  ushort_t* Wqh = (ushort_t*)(ws + O_ATTN);  ushort_t* Wql = Wqh + WQ_TOTAL;
  ushort_t* Wm  = (ushort_t*)(ws + O_XN);

  // stage0: adaln(48) + mod(64) + Wqkv split(1536) — all input-only deps
  hipLaunchKernelGGL(k_stage0, dim3(48 + 64 + 1536), dim3(256), 0, stream,
                     vec, t_aw, t_ab, i_aw, i_ab, sspat, modw, modb, stemp,
                     t_qkvw, i_qkvw, ws);
  hipLaunchKernelGGL((k_rmsmod<true>), dim3(MROWS), dim3(256), 0, stream,
                     txt, img, (const float*)nullptr, t_anw, i_anw, 0, 512, ws, XNh, XNl);
  // QKV: MTILE=64 -> 960 blocks, 3-term, K=512. Fused epilogue: rope+mod,
  // Q pre-scaled bf16 hi/lo planes -> O_Q, K bf16 hi/lo planes -> O_XIN2, V f32.
  hipLaunchKernelGGL((k_gemm<64, 128, 3, 512, 12, 0>), dim3(80 * 12), dim3(256), 0, stream,
                     XNh, XNl, Wqh, Wql, Wqh + WQ_STREAM, Wql + WQ_STREAM,
                     rope, nullptr, ws, ws, txt, img,
                     (ushort_t*)nullptr, (ushort_t*)nullptr, nullptr);
  // stage1: vt(320) + Wmlp split(4608)
  hipLaunchKernelGGL(k_stage1, dim3(320 + 4608), dim3(256), 0, stream,
                     ws, t_outw, i_outw, t_f1w, i_f1w, t_f2w, i_f2w);
  // attn partials: 3-way K-split, Q planes, regular partial stores
  hipLaunchKernelGGL(k_attn13, dim3(960), dim3(256), 0, stream, ws, ws);
  // combine partials -> attn planes at O_Q
  hipLaunchKernelGGL(k_comb, dim3(320), dim3(256), 0, stream, ws, ws);
  // proj: MTILE=64 -> 640 blocks, 2-term, K=512
  hipLaunchKernelGGL((k_gemm<64, 64, 2, 512, 8, 1>), dim3(80 * 8), dim3(256), 0, stream,
                     ATh, ATl, Wm + WM_PROJ, nullptr, Wm + WM_PROJ + WM_PROJ_S, nullptr,
                     nullptr, nullptr, ws, ws, txt, img,
                     (ushort_t*)nullptr, (ushort_t*)nullptr, nullptr);
  hipLaunchKernelGGL((k_rmsmod<false>), dim3(MROWS), dim3(256), 0, stream,
                     (const float*)nullptr, (const float*)nullptr, ws + O_X2, t_n2w, i_n2w,
                     1536, 2048, ws, XI2h, XI2l);
  // fc1: MTILE=64 -> 1280 blocks, 2-term, K=512
  hipLaunchKernelGGL((k_gemm<64, 128, 2, 512, 16, 2>), dim3(80 * 16), dim3(256), 0, stream,
                     XI2h, XI2l, Wm + WM_FC1, nullptr, Wm + WM_FC1 + WM_FC1_S, nullptr,
                     t_f1b, i_f1b, ws, ws, txt, img, Hh, Hl, nullptr);
  // fc2: MTILE=64 -> 640 blocks, 2-term, K=2048
  hipLaunchKernelGGL((k_gemm<64, 64, 2, 2048, 8, 3>), dim3(80 * 8), dim3(256), 0, stream,
                     Hh, Hl, Wm + WM_FC2, nullptr, Wm + WM_FC2 + WM_FC2_S, nullptr,
                     t_f2b, i_f2b, ws, ws, txt, img,
                     (ushort_t*)nullptr, (ushort_t*)nullptr, out);
}